// Round 1
// baseline (265.578 us; speedup 1.0000x reference)
//
#include <hip/hip_runtime.h>
#include <hip/hip_bf16.h>

// ConvolutionalSelfAttention — algebraically reduced:
//   Kn[b,n,:] = normalize(x[b,n,:] @ key_w^T + key_b)      (bf16 in ws)
//   Qn[b,m,:] = normalize(x[b,m,:] @ query_w^T + query_b)  (bf16 in ws)
//   v[b,n]    = x[b,n,:] @ value_w^T + value_b             (fp32 in ws)
//   S[b,n,m]  = Kn[b,n]·Qn[b,m]   (|S|<=1, exp is stable without max-sub)
//   R[b,m]    = (sum_n v[b,n] e^{S}) / (sum_n e^{S})       (fused, S never stored)
//   out[b,c,i,j] = sum_{3x3 window m} R[b,m] * batch[b,c,m]
// local_indices (d_in[7]) is provably just the sorted 3x3 windows -> unused.
// Workspace: 8MB Kn + 8MB Qn + 64KB v + 64KB R  (~16.9 MB)

#define NB 16
#define NC 256
#define NHW 1024
#define NCH 30

typedef __attribute__((ext_vector_type(8))) short short8;
typedef __attribute__((ext_vector_type(4))) float f32x4;

__global__ __launch_bounds__(256) void lin_kernel(
    const float* __restrict__ batch,
    const float* __restrict__ key_w, const float* __restrict__ key_b,
    const float* __restrict__ query_w, const float* __restrict__ query_b,
    const float* __restrict__ value_w, const float* __restrict__ value_b,
    __hip_bfloat16* __restrict__ Kn, __hip_bfloat16* __restrict__ Qn,
    float* __restrict__ vout)
{
    const int b  = blockIdx.y;
    const int n0 = blockIdx.x * 16;   // 16 spatial positions per block
    const int t  = threadIdx.x;

    __shared__ float Xs[16][260];     // [pos][channel], padded (260*4 % 16 == 0)
    __shared__ float normsK[16], normsQ[16];

    // Load X tile transposed: Xs[p][c] = batch[b, c, n0+p]
    {
        const float* bb = batch + (size_t)b * NC * NHW + n0;
        int p = t & 15, cr = t >> 4;
        for (int it = 0; it < 16; ++it) {
            int c = cr + it * 16;
            Xs[p][c] = bb[(size_t)c * NHW + p];
        }
    }
    __syncthreads();

    // values: v[b, n0+p] = Xs[p,:]·value_w + value_b
    {
        int vp = t >> 4, c0 = (t & 15) * 16;
        float s = 0.f;
        #pragma unroll
        for (int j = 0; j < 16; ++j) s += Xs[vp][c0 + j] * value_w[c0 + j];
        #pragma unroll
        for (int o = 1; o < 16; o <<= 1) s += __shfl_xor(s, o, 64);
        if ((t & 15) == 0) vout[b * NHW + n0 + vp] = s + value_b[0];
    }

    // keys/queries: thread t owns output channel t for all 16 positions
    float accK[16], accQ[16];
    {
        float kb = key_b[t], qb = query_b[t];
        #pragma unroll
        for (int p = 0; p < 16; ++p) { accK[p] = kb; accQ[p] = qb; }
    }
    const float* kwr = key_w + (size_t)t * NC;
    const float* qwr = query_w + (size_t)t * NC;
    for (int c = 0; c < NC; c += 4) {
        float4 wk = *(const float4*)(kwr + c);
        float4 wq = *(const float4*)(qwr + c);
        #pragma unroll
        for (int p = 0; p < 16; ++p) {
            float4 xv = *(const float4*)(&Xs[p][c]);   // broadcast ds_read_b128
            accK[p] += xv.x*wk.x + xv.y*wk.y + xv.z*wk.z + xv.w*wk.w;
            accQ[p] += xv.x*wq.x + xv.y*wq.y + xv.z*wq.z + xv.w*wq.w;
        }
    }
    __syncthreads();

    // row norms of keys
    #pragma unroll
    for (int p = 0; p < 16; ++p) Xs[p][t] = accK[p] * accK[p];
    __syncthreads();
    {
        int vp = t >> 4, c0 = (t & 15) * 16;
        float s = 0.f;
        #pragma unroll
        for (int j = 0; j < 16; ++j) s += Xs[vp][c0 + j];
        #pragma unroll
        for (int o = 1; o < 16; o <<= 1) s += __shfl_xor(s, o, 64);
        if ((t & 15) == 0) normsK[vp] = s;
    }
    __syncthreads();
    // row norms of queries
    #pragma unroll
    for (int p = 0; p < 16; ++p) Xs[p][t] = accQ[p] * accQ[p];
    __syncthreads();
    {
        int vp = t >> 4, c0 = (t & 15) * 16;
        float s = 0.f;
        #pragma unroll
        for (int j = 0; j < 16; ++j) s += Xs[vp][c0 + j];
        #pragma unroll
        for (int o = 1; o < 16; o <<= 1) s += __shfl_xor(s, o, 64);
        if ((t & 15) == 0) normsQ[vp] = s;
    }
    __syncthreads();

    #pragma unroll
    for (int p = 0; p < 16; ++p) {
        float ik = 1.f / fmaxf(sqrtf(normsK[p]), 1e-12f);
        float iq = 1.f / fmaxf(sqrtf(normsQ[p]), 1e-12f);
        size_t row = (size_t)(b * NHW + n0 + p) * NC + t;
        Kn[row] = __float2bfloat16(accK[p] * ik);
        Qn[row] = __float2bfloat16(accQ[p] * iq);
    }
}

// Per (b, 64 m-columns): S-tile via MFMA, online-reduce Z and T over n.
// wave w of 8: m-subtile = w&3 (16 cols), n-half = w>>2 (512 rows).
__global__ __launch_bounds__(512) void attn_kernel(
    const __hip_bfloat16* __restrict__ Kn,
    const __hip_bfloat16* __restrict__ Qn,
    const float* __restrict__ vbuf,
    float* __restrict__ R)
{
    const int b    = blockIdx.y;
    const int m0   = blockIdx.x * 64;
    const int t    = threadIdx.x;
    const int wave = t >> 6, lane = t & 63;
    const int msub = wave & 3, nhalf = wave >> 2;
    const int mbase = m0 + msub * 16;
    const int l15 = lane & 15, quad = lane >> 4;

    // Preload B-fragments (Qn rows = B^T rows): B[k=c][col=m], lane: m=l15, k=quad*8+j
    short8 bfrag[8];
    {
        const short* qrow = (const short*)Qn + ((size_t)(b * NHW + mbase + l15)) * NC + quad * 8;
        #pragma unroll
        for (int c = 0; c < 8; ++c) bfrag[c] = *(const short8*)(qrow + 32 * c);
    }
    const short* karow = (const short*)Kn + ((size_t)(b * NHW + l15)) * NC + quad * 8;
    const float* vb = vbuf + b * NHW;

    float zacc = 0.f, tacc = 0.f;
    const int nend = nhalf * 512 + 512;
    for (int n0 = nhalf * 512; n0 < nend; n0 += 16) {
        f32x4 acc = {0.f, 0.f, 0.f, 0.f};
        const short* ka = karow + (size_t)n0 * NC;
        #pragma unroll
        for (int c = 0; c < 8; ++c) {
            short8 af = *(const short8*)(ka + 32 * c);  // A: row n=l15, k=quad*8+j
            acc = __builtin_amdgcn_mfma_f32_16x16x32_bf16(af, bfrag[c], acc, 0, 0, 0);
        }
        // C/D layout: col = l15 (m), row = quad*4 + r (n within tile)
        float4 vv = *(const float4*)(vb + n0 + quad * 4);
        #pragma unroll
        for (int r = 0; r < 4; ++r) {
            float e = __expf(acc[r]);
            zacc += e;
            tacc += ((const float*)&vv)[r] * e;
        }
    }
    // reduce over quads (rows) -> per-column (m) sums
    zacc += __shfl_xor(zacc, 16, 64); zacc += __shfl_xor(zacc, 32, 64);
    tacc += __shfl_xor(tacc, 16, 64); tacc += __shfl_xor(tacc, 32, 64);

    __shared__ float zs[8][16], ts[8][16];
    if (lane < 16) { zs[wave][l15] = zacc; ts[wave][l15] = tacc; }
    __syncthreads();
    if (t < 64) {
        int ms = t >> 4, li = t & 15;
        float z  = zs[ms][li] + zs[ms + 4][li];
        float tt = ts[ms][li] + ts[ms + 4][li];
        R[b * NHW + m0 + ms * 16 + li] = tt / z;
    }
}

// out[b,c,i,j] = 3x3 box sum over P[m] = R[b,m]*batch[b,c,m]
__global__ __launch_bounds__(256) void out_kernel(
    const float* __restrict__ batch,
    const float* __restrict__ R,
    float* __restrict__ out)
{
    const int bc = blockIdx.x;          // b*256 + c
    const int b  = bc >> 8;
    const int t  = threadIdx.x;
    __shared__ float P[NHW];

    const float* bp = batch + (size_t)bc * NHW;
    const float* rp = R + b * NHW;
    #pragma unroll
    for (int k = 0; k < 4; ++k) {
        int m = t + 256 * k;
        P[m] = rp[m] * bp[m];
    }
    __syncthreads();
    for (int idx = t; idx < NCH * NCH; idx += 256) {
        int i = idx / NCH, j = idx - i * NCH;
        const float* pr = &P[i * 32 + j];
        float s = pr[0]  + pr[1]  + pr[2]
                + pr[32] + pr[33] + pr[34]
                + pr[64] + pr[65] + pr[66];
        out[(size_t)bc * (NCH * NCH) + idx] = s;
    }
}

extern "C" void kernel_launch(void* const* d_in, const int* in_sizes, int n_in,
                              void* d_out, int out_size, void* d_ws, size_t ws_size,
                              hipStream_t stream) {
    const float* batch   = (const float*)d_in[0];
    const float* key_w   = (const float*)d_in[1];
    const float* key_b   = (const float*)d_in[2];
    const float* query_w = (const float*)d_in[3];
    const float* query_b = (const float*)d_in[4];
    const float* value_w = (const float*)d_in[5];
    const float* value_b = (const float*)d_in[6];
    // d_in[7] (local_indices) unused — windows are complete 3x3, order-invariant.
    float* out = (float*)d_out;

    char* ws = (char*)d_ws;
    const size_t KQ = (size_t)NB * NHW * NC;            // 4,194,304 elems
    __hip_bfloat16* Kn = (__hip_bfloat16*)ws;
    __hip_bfloat16* Qn = Kn + KQ;
    float* vbuf = (float*)(ws + 2 * KQ * sizeof(__hip_bfloat16));
    float* Rbuf = vbuf + NB * NHW;

    lin_kernel<<<dim3(64, NB), 256, 0, stream>>>(batch, key_w, key_b, query_w, query_b,
                                                 value_w, value_b, Kn, Qn, vbuf);
    attn_kernel<<<dim3(16, NB), 512, 0, stream>>>(Kn, Qn, vbuf, Rbuf);
    out_kernel<<<NB * NC, 256, 0, stream>>>(batch, Rbuf, out);
}

// Round 2
// 166.600 us; speedup vs baseline: 1.5941x; 1.5941x over previous
//
#include <hip/hip_runtime.h>
#include <hip/hip_bf16.h>

// ConvolutionalSelfAttention — algebraically reduced:
//   Kn[b,n,:] = normalize(x[b,n,:] @ key_w^T + key_b)      (bf16, via MFMA)
//   Qn[b,m,:] = normalize(x[b,m,:] @ query_w^T + query_b)  (bf16, via MFMA)
//   v[b,n]    = x[b,n,:] @ value_w^T + value_b             (fp32)
//   S[b,n,m]  = Kn[b,n]·Qn[b,m]   (|S|<=1, exp stable without max-sub)
//   R[b,m]    = (sum_n v e^S) / (sum_n e^S)                (fused, S never stored)
//   out[b,c,i,j] = 3x3 box sum of R[b,m]*batch[b,c,m]
// local_indices unused (windows are complete 3x3, order-invariant).
// ws: xb 8MB | Kn 8MB | Qn 8MB | kwb 128KB | qwb 128KB | v 64KB | R 64KB

#define NB 16
#define NC 256
#define NHW 1024
#define NCH 30

typedef __attribute__((ext_vector_type(8))) short short8;
typedef __attribute__((ext_vector_type(8))) unsigned short ushort8v;
typedef __attribute__((ext_vector_type(4))) float f32x4;

static __device__ __forceinline__ unsigned short f2bf(float f) {
    __hip_bfloat16 h = __float2bfloat16(f);
    return *(unsigned short*)&h;
}

// Blocks 0..255: transpose batch[b,c,n]->xb[b,n,c] (bf16) + v[b,n].
// Blocks 256..271: convert key_w/query_w fp32->bf16.
__global__ __launch_bounds__(256) void prep_kernel(
    const float* __restrict__ batch,
    const float* __restrict__ value_w, const float* __restrict__ value_b,
    const float* __restrict__ key_w, const float* __restrict__ query_w,
    unsigned short* __restrict__ xb, float* __restrict__ vout,
    unsigned short* __restrict__ kwb, unsigned short* __restrict__ qwb)
{
    const int gx = blockIdx.x;
    const int t  = threadIdx.x;

    if (gx >= 256) {  // weight conversion
        int idx = gx - 256;                    // 0..15
        const float* src = (idx >> 3) ? query_w : key_w;
        unsigned short* dst = (idx >> 3) ? qwb : kwb;
        int base = (idx & 7) * 8192;
        #pragma unroll
        for (int k = 0; k < 8; ++k) {
            int i = base + (k * 256 + t) * 4;
            float4 a = *(const float4*)(src + i);
            ushort4 o;
            o.x = f2bf(a.x); o.y = f2bf(a.y); o.z = f2bf(a.z); o.w = f2bf(a.w);
            *(ushort4*)(dst + i) = o;
        }
        return;
    }

    const int b  = gx >> 4;
    const int n0 = (gx & 15) * 64;

    __shared__ float Xs[64][65];
    __shared__ float vw_s[NC];
    vw_s[t] = value_w[t];

    const float* bb = batch + (size_t)b * NC * NHW + n0;
    const int n_l = t & 63, c_g = t >> 6;   // load mapping
    const int wn = t >> 2, cg = t & 3;      // write mapping
    float vacc = 0.f;
    unsigned short* xrow = xb + (size_t)(b * NHW + n0 + wn) * NC;

    for (int cc = 0; cc < 4; ++cc) {
        __syncthreads();
        #pragma unroll
        for (int s = 0; s < 16; ++s) {
            int c = cc * 64 + s * 4 + c_g;
            Xs[s * 4 + c_g][n_l] = bb[(size_t)c * NHW + n_l];
        }
        __syncthreads();
        ushort8v p0, p1;
        float vloc = 0.f;
        #pragma unroll
        for (int j = 0; j < 8; ++j) {
            float v0 = Xs[cg * 16 + j][wn];
            float v1 = Xs[cg * 16 + 8 + j][wn];
            p0[j] = f2bf(v0); p1[j] = f2bf(v1);
            vloc += v0 * vw_s[cc * 64 + cg * 16 + j]
                  + v1 * vw_s[cc * 64 + cg * 16 + 8 + j];
        }
        vacc += vloc;
        ushort8v* dst = (ushort8v*)(xrow + cc * 64 + cg * 16);
        dst[0] = p0; dst[1] = p1;
    }
    vacc += __shfl_xor(vacc, 1, 64);
    vacc += __shfl_xor(vacc, 2, 64);
    if (cg == 0) vout[b * NHW + n0 + wn] = vacc + value_b[0];
}

// MFMA GEMM: Kn/Qn = normalize(xb @ w^T + bias). 8 waves: (nw 0..3, co-half 0..1).
__global__ __launch_bounds__(512) void lin_kernel(
    const unsigned short* __restrict__ xb,
    const unsigned short* __restrict__ kwb, const unsigned short* __restrict__ qwb,
    const float* __restrict__ key_b, const float* __restrict__ query_b,
    unsigned short* __restrict__ Kn, unsigned short* __restrict__ Qn)
{
    const int b = blockIdx.y, n0 = blockIdx.x * 64;
    const int t = threadIdx.x, wave = t >> 6, lane = t & 63;
    const int nw = wave & 3, ch = wave >> 2;
    const int l15 = lane & 15, quad = lane >> 4;
    const int nbase = n0 + nw * 16;

    short8 af[8];
    {
        const short* xr = (const short*)xb + (size_t)(b * NHW + nbase + l15) * NC + quad * 8;
        #pragma unroll
        for (int c = 0; c < 8; ++c) af[c] = *(const short8*)(xr + 32 * c);
    }

    f32x4 accK[8], accQ[8];
    #pragma unroll
    for (int ct = 0; ct < 8; ++ct) {
        int co = ch * 128 + ct * 16 + l15;
        float bK = key_b[co], bQ = query_b[co];
        accK[ct] = (f32x4){bK, bK, bK, bK};
        accQ[ct] = (f32x4){bQ, bQ, bQ, bQ};
        const short* kr = (const short*)kwb + (size_t)co * NC + quad * 8;
        const short* qr = (const short*)qwb + (size_t)co * NC + quad * 8;
        #pragma unroll
        for (int c = 0; c < 8; ++c) {
            short8 bk = *(const short8*)(kr + 32 * c);
            short8 bq = *(const short8*)(qr + 32 * c);
            accK[ct] = __builtin_amdgcn_mfma_f32_16x16x32_bf16(af[c], bk, accK[ct], 0, 0, 0);
            accQ[ct] = __builtin_amdgcn_mfma_f32_16x16x32_bf16(af[c], bq, accQ[ct], 0, 0, 0);
        }
    }

    // row-norm partials: rows n = nbase + quad*4 + r, cols = this wave's 128 co
    float nK[4] = {0, 0, 0, 0}, nQ[4] = {0, 0, 0, 0};
    #pragma unroll
    for (int ct = 0; ct < 8; ++ct)
        #pragma unroll
        for (int r = 0; r < 4; ++r) {
            nK[r] += accK[ct][r] * accK[ct][r];
            nQ[r] += accQ[ct][r] * accQ[ct][r];
        }
    #pragma unroll
    for (int r = 0; r < 4; ++r)
        #pragma unroll
        for (int o = 1; o < 16; o <<= 1) {
            nK[r] += __shfl_xor(nK[r], o, 64);
            nQ[r] += __shfl_xor(nQ[r], o, 64);
        }

    __shared__ float PK[2][4][16], PQ[2][4][16];
    if (l15 == 0)
        #pragma unroll
        for (int r = 0; r < 4; ++r) {
            PK[ch][nw][quad * 4 + r] = nK[r];
            PQ[ch][nw][quad * 4 + r] = nQ[r];
        }
    __syncthreads();

    float ik[4], iq[4];
    #pragma unroll
    for (int r = 0; r < 4; ++r) {
        float sk = PK[0][nw][quad * 4 + r] + PK[1][nw][quad * 4 + r];
        float sq = PQ[0][nw][quad * 4 + r] + PQ[1][nw][quad * 4 + r];
        ik[r] = 1.f / fmaxf(sqrtf(sk), 1e-12f);
        iq[r] = 1.f / fmaxf(sqrtf(sq), 1e-12f);
    }
    #pragma unroll
    for (int ct = 0; ct < 8; ++ct)
        #pragma unroll
        for (int r = 0; r < 4; ++r) {
            size_t row = (size_t)(b * NHW + nbase + quad * 4 + r) * NC + ch * 128 + ct * 16 + l15;
            Kn[row] = f2bf(accK[ct][r] * ik[r]);
            Qn[row] = f2bf(accQ[ct][r] * iq[r]);
        }
}

// Per (b, 32 m-cols): 4 waves each own an n-quarter; 4 independent MFMA chains.
__global__ __launch_bounds__(256) void attn_kernel(
    const unsigned short* __restrict__ Kn,
    const unsigned short* __restrict__ Qn,
    const float* __restrict__ vbuf,
    float* __restrict__ R)
{
    const int b = blockIdx.y, m0 = blockIdx.x * 32;
    const int t = threadIdx.x, wave = t >> 6, lane = t & 63;
    const int l15 = lane & 15, quad = lane >> 4;

    short8 bf0[8], bf1[8];
    {
        const short* q0 = (const short*)Qn + (size_t)(b * NHW + m0 + l15) * NC + quad * 8;
        const short* q1 = q0 + 16 * NC;
        #pragma unroll
        for (int c = 0; c < 8; ++c) { bf0[c] = *(const short8*)(q0 + 32 * c);
                                      bf1[c] = *(const short8*)(q1 + 32 * c); }
    }
    const float* vb = vbuf + b * NHW;
    const int nstart = wave * 256;
    const short* ka = (const short*)Kn + (size_t)(b * NHW + nstart + l15) * NC + quad * 8;

    float z0 = 0.f, t0 = 0.f, z1 = 0.f, t1 = 0.f;
    for (int it = 0; it < 16; ++it, ka += 16 * NC) {
        short8 af[8];
        #pragma unroll
        for (int c = 0; c < 8; ++c) af[c] = *(const short8*)(ka + 32 * c);
        f32x4 a00 = {0,0,0,0}, a01 = {0,0,0,0}, a10 = {0,0,0,0}, a11 = {0,0,0,0};
        #pragma unroll
        for (int c = 0; c < 4; ++c) {
            a00 = __builtin_amdgcn_mfma_f32_16x16x32_bf16(af[c],     bf0[c],     a00, 0, 0, 0);
            a10 = __builtin_amdgcn_mfma_f32_16x16x32_bf16(af[c],     bf1[c],     a10, 0, 0, 0);
            a01 = __builtin_amdgcn_mfma_f32_16x16x32_bf16(af[c + 4], bf0[c + 4], a01, 0, 0, 0);
            a11 = __builtin_amdgcn_mfma_f32_16x16x32_bf16(af[c + 4], bf1[c + 4], a11, 0, 0, 0);
        }
        float4 vv = *(const float4*)(vb + nstart + it * 16 + quad * 4);
        #pragma unroll
        for (int r = 0; r < 4; ++r) {
            float e0 = __expf(a00[r] + a01[r]);
            float e1 = __expf(a10[r] + a11[r]);
            float vr = ((const float*)&vv)[r];
            z0 += e0; t0 += vr * e0;
            z1 += e1; t1 += vr * e1;
        }
    }
    z0 += __shfl_xor(z0, 16, 64); z0 += __shfl_xor(z0, 32, 64);
    t0 += __shfl_xor(t0, 16, 64); t0 += __shfl_xor(t0, 32, 64);
    z1 += __shfl_xor(z1, 16, 64); z1 += __shfl_xor(z1, 32, 64);
    t1 += __shfl_xor(t1, 16, 64); t1 += __shfl_xor(t1, 32, 64);

    __shared__ float zs[4][2][16], ts[4][2][16];
    if (lane < 16) {
        zs[wave][0][l15] = z0; ts[wave][0][l15] = t0;
        zs[wave][1][l15] = z1; ts[wave][1][l15] = t1;
    }
    __syncthreads();
    if (t < 32) {
        int ms = t >> 4, li = t & 15;
        float z = 0.f, tt = 0.f;
        #pragma unroll
        for (int w = 0; w < 4; ++w) { z += zs[w][ms][li]; tt += ts[w][ms][li]; }
        R[b * NHW + m0 + ms * 16 + li] = tt / z;
    }
}

// out[b,c,i,j] = 3x3 box sum over P[m] = R[b,m]*batch[b,c,m]
__global__ __launch_bounds__(256) void out_kernel(
    const float* __restrict__ batch,
    const float* __restrict__ R,
    float* __restrict__ out)
{
    const int bc = blockIdx.x;
    const int b  = bc >> 8;
    const int t  = threadIdx.x;
    __shared__ float P[NHW];

    const float* bp = batch + (size_t)bc * NHW;
    const float* rp = R + b * NHW;
    #pragma unroll
    for (int k = 0; k < 4; ++k) {
        int m = t + 256 * k;
        P[m] = rp[m] * bp[m];
    }
    __syncthreads();
    for (int idx = t; idx < NCH * NCH; idx += 256) {
        int i = idx / NCH, j = idx - i * NCH;
        const float* pr = &P[i * 32 + j];
        float s = pr[0]  + pr[1]  + pr[2]
                + pr[32] + pr[33] + pr[34]
                + pr[64] + pr[65] + pr[66];
        out[(size_t)bc * (NCH * NCH) + idx] = s;
    }
}

extern "C" void kernel_launch(void* const* d_in, const int* in_sizes, int n_in,
                              void* d_out, int out_size, void* d_ws, size_t ws_size,
                              hipStream_t stream) {
    const float* batch   = (const float*)d_in[0];
    const float* key_w   = (const float*)d_in[1];
    const float* key_b   = (const float*)d_in[2];
    const float* query_w = (const float*)d_in[3];
    const float* query_b = (const float*)d_in[4];
    const float* value_w = (const float*)d_in[5];
    const float* value_b = (const float*)d_in[6];
    float* out = (float*)d_out;

    char* ws = (char*)d_ws;
    const size_t KQ = (size_t)NB * NHW * NC;            // 4,194,304 elems
    unsigned short* xbuf = (unsigned short*)ws;                       // 8MB
    unsigned short* Kn   = xbuf + KQ;                                 // 8MB
    unsigned short* Qn   = Kn + KQ;                                   // 8MB
    unsigned short* kwb  = Qn + KQ;                                   // 128KB
    unsigned short* qwb  = kwb + NC * NC;                             // 128KB
    float* vbuf = (float*)(qwb + NC * NC);                            // 64KB
    float* Rbuf = vbuf + NB * NHW;                                    // 64KB

    prep_kernel<<<272, 256, 0, stream>>>(batch, value_w, value_b, key_w, query_w,
                                         xbuf, vbuf, kwb, qwb);
    lin_kernel<<<dim3(16, NB), 512, 0, stream>>>(xbuf, kwb, qwb, key_b, query_b, Kn, Qn);
    attn_kernel<<<dim3(32, NB), 256, 0, stream>>>(Kn, Qn, vbuf, Rbuf);
    out_kernel<<<NB * NC, 256, 0, stream>>>(batch, Rbuf, out);
}

// Round 4
// 158.911 us; speedup vs baseline: 1.6712x; 1.0484x over previous
//
#include <hip/hip_runtime.h>
#include <hip/hip_bf16.h>

// ConvolutionalSelfAttention — algebraically reduced:
//   Kn[b,n,:] = normalize(x[b,n,:] @ key_w^T + key_b)      (bf16, via MFMA)
//   Qn[b,m,:] = normalize(x[b,m,:] @ query_w^T + query_b)  (bf16, via MFMA)
//   v[b,n]    = x[b,n,:] @ value_w^T + value_b             (fp32)
//   S[b,n,m]  = Kn[b,n]·Qn[b,m]   (|S|<=1, exp stable without max-sub)
//   R[b,m]    = (sum_n v e^S) / (sum_n e^S)                (fused, S never stored)
//   out[b,c,i,j] = 3x3 box sum of R[b,m]*x[b,c,m]  (x in bf16 copy xc)
// local_indices unused (windows are complete 3x3, order-invariant).
// R3->R4 FIX: v-reduction was missing the cross-quad shfl (each wave's lanes
// 16..63 hold 3/4 of the channel partials) -> v was ~1/4 scale, absmax 0.477.
// ws: xc 8MB | Kn 8MB | Qn 8MB | kwb 128KB | qwb 128KB | v 64KB | R 64KB

#define NB 16
#define NC 256
#define NHW 1024
#define NCH 30

typedef __attribute__((ext_vector_type(8))) short short8;
typedef __attribute__((ext_vector_type(4))) float f32x4;

static __device__ __forceinline__ unsigned short f2bf(float f) {
    __hip_bfloat16 h = __float2bfloat16(f);
    return *(unsigned short*)&h;
}
static __device__ __forceinline__ float bf2f(unsigned short u) {
    unsigned int x = ((unsigned int)u) << 16;
    return __uint_as_float(x);
}

// fp32 -> bf16 weight conversion (32 blocks: 16 per matrix)
__global__ __launch_bounds__(256) void wconv_kernel(
    const float* __restrict__ key_w, const float* __restrict__ query_w,
    unsigned short* __restrict__ kwb, unsigned short* __restrict__ qwb)
{
    const int gx = blockIdx.x, t = threadIdx.x;
    const float* src = (gx < 16) ? key_w : query_w;
    unsigned short* dst = (gx < 16) ? kwb : qwb;
    int base = (gx & 15) * 4096;
    #pragma unroll
    for (int k = 0; k < 4; ++k) {
        int i = base + (k * 256 + t) * 4;
        float4 a = *(const float4*)(src + i);
        ushort4 o;
        o.x = f2bf(a.x); o.y = f2bf(a.y); o.z = f2bf(a.z); o.w = f2bf(a.w);
        *(ushort4*)(dst + i) = o;
    }
}

// Fused: transpose batch -> (LDS fp32 slab, xc bf16 copy) + v + MFMA linears
// + row-normalize -> Kn, Qn.  Grid (16 n-tiles, B), 512 threads (8 waves:
// nw = wave&3 picks 16-row n-subtile, ch = wave>>2 picks 128-col co-half).
__global__ __launch_bounds__(512) void fused_lin_kernel(
    const float* __restrict__ batch,
    const float* __restrict__ value_w, const float* __restrict__ value_b,
    const unsigned short* __restrict__ kwb, const unsigned short* __restrict__ qwb,
    const float* __restrict__ key_b, const float* __restrict__ query_b,
    unsigned short* __restrict__ xc,
    unsigned short* __restrict__ Kn, unsigned short* __restrict__ Qn,
    float* __restrict__ vout)
{
    const int b = blockIdx.y, n0 = blockIdx.x * 64;
    const int t = threadIdx.x, wave = t >> 6, lane = t & 63;
    const int nw = wave & 3, ch = wave >> 2;
    const int l15 = lane & 15, quad = lane >> 4;

    __shared__ float Xs[2][64][65];          // [buf][k-in-slab][n], stride 65
    __shared__ float PK[2][4][16], PQ[2][4][16];
    __shared__ float4 vred[8][16];

    // staging roles: thread loads rows c_l and c_l+32 of the 64-c slab, 4 n's
    const int c_l = t >> 4;                  // 0..31  (= wave*4 + quad)
    const int n4  = (t & 15) * 4;
    const float* bb = batch + (size_t)b * NC * NHW + n0;
    unsigned short* xcp = xc + (size_t)b * NC * NHW + n0;
    float4 vacc = {0.f, 0.f, 0.f, 0.f};

    float4 x0, x1;
    // prologue: load slab 0
    {
        int c0 = c_l, c1 = c_l + 32;
        x0 = *(const float4*)(bb + (size_t)c0 * NHW + n4);
        x1 = *(const float4*)(bb + (size_t)c1 * NHW + n4);
        ushort4 o0, o1;
        o0.x = f2bf(x0.x); o0.y = f2bf(x0.y); o0.z = f2bf(x0.z); o0.w = f2bf(x0.w);
        o1.x = f2bf(x1.x); o1.y = f2bf(x1.y); o1.z = f2bf(x1.z); o1.w = f2bf(x1.w);
        *(ushort4*)(xcp + (size_t)c0 * NHW + n4) = o0;
        *(ushort4*)(xcp + (size_t)c1 * NHW + n4) = o1;
        float w0 = value_w[c0], w1 = value_w[c1];
        vacc.x += x0.x * w0 + x1.x * w1; vacc.y += x0.y * w0 + x1.y * w1;
        vacc.z += x0.z * w0 + x1.z * w1; vacc.w += x0.w * w0 + x1.w * w1;
        float* r0 = &Xs[0][c_l][n4];
        r0[0] = x0.x; r0[1] = x0.y; r0[2] = x0.z; r0[3] = x0.w;
        float* r1 = &Xs[0][c_l + 32][n4];
        r1[0] = x1.x; r1[1] = x1.y; r1[2] = x1.z; r1[3] = x1.w;
    }
    __syncthreads();

    f32x4 accK[8], accQ[8];
    #pragma unroll
    for (int ct = 0; ct < 8; ++ct) {
        int co = ch * 128 + ct * 16 + l15;
        float bK = key_b[co], bQ = query_b[co];
        accK[ct] = (f32x4){bK, bK, bK, bK};
        accQ[ct] = (f32x4){bQ, bQ, bQ, bQ};
    }

    for (int cc = 0; cc < 4; ++cc) {
        // prefetch next slab into registers (latency hidden by MFMA below)
        if (cc < 3) {
            int c0 = (cc + 1) * 64 + c_l, c1 = c0 + 32;
            x0 = *(const float4*)(bb + (size_t)c0 * NHW + n4);
            x1 = *(const float4*)(bb + (size_t)c1 * NHW + n4);
            ushort4 o0, o1;
            o0.x = f2bf(x0.x); o0.y = f2bf(x0.y); o0.z = f2bf(x0.z); o0.w = f2bf(x0.w);
            o1.x = f2bf(x1.x); o1.y = f2bf(x1.y); o1.z = f2bf(x1.z); o1.w = f2bf(x1.w);
            *(ushort4*)(xcp + (size_t)c0 * NHW + n4) = o0;
            *(ushort4*)(xcp + (size_t)c1 * NHW + n4) = o1;
            float w0 = value_w[c0], w1 = value_w[c1];
            vacc.x += x0.x * w0 + x1.x * w1; vacc.y += x0.y * w0 + x1.y * w1;
            vacc.z += x0.z * w0 + x1.z * w1; vacc.w += x0.w * w0 + x1.w * w1;
        }
        // compute: 2 k-chunks of 32 from current slab
        const int cur = cc & 1;
        #pragma unroll
        for (int kc = 0; kc < 2; ++kc) {
            short8 af;
            #pragma unroll
            for (int j = 0; j < 8; ++j)
                af[j] = (short)f2bf(Xs[cur][kc * 32 + quad * 8 + j][nw * 16 + l15]);
            const int g = cc * 2 + kc;       // global k-chunk 0..7
            #pragma unroll
            for (int ct = 0; ct < 8; ++ct) {
                int co = ch * 128 + ct * 16 + l15;
                const short* kr = (const short*)kwb + (size_t)co * NC + quad * 8;
                const short* qr = (const short*)qwb + (size_t)co * NC + quad * 8;
                short8 bk = *(const short8*)(kr + 32 * g);
                short8 bq = *(const short8*)(qr + 32 * g);
                accK[ct] = __builtin_amdgcn_mfma_f32_16x16x32_bf16(af, bk, accK[ct], 0, 0, 0);
                accQ[ct] = __builtin_amdgcn_mfma_f32_16x16x32_bf16(af, bq, accQ[ct], 0, 0, 0);
            }
        }
        if (cc < 3) {
            const int nxt = (cc + 1) & 1;
            float* r0 = &Xs[nxt][c_l][n4];
            r0[0] = x0.x; r0[1] = x0.y; r0[2] = x0.z; r0[3] = x0.w;
            float* r1 = &Xs[nxt][c_l + 32][n4];
            r1[0] = x1.x; r1[1] = x1.y; r1[2] = x1.z; r1[3] = x1.w;
            __syncthreads();
        }
    }

    // v: reduce across quads within the wave (lanes with same l15 hold
    // different channels) — THE R3 BUG was omitting this step.
    vacc.x += __shfl_xor(vacc.x, 16, 64); vacc.x += __shfl_xor(vacc.x, 32, 64);
    vacc.y += __shfl_xor(vacc.y, 16, 64); vacc.y += __shfl_xor(vacc.y, 32, 64);
    vacc.z += __shfl_xor(vacc.z, 16, 64); vacc.z += __shfl_xor(vacc.z, 32, 64);
    vacc.w += __shfl_xor(vacc.w, 16, 64); vacc.w += __shfl_xor(vacc.w, 32, 64);

    // row-norm partials: rows n = n0 + nw*16 + quad*4 + r, cols = wave's 128 co
    float nK[4] = {0, 0, 0, 0}, nQ[4] = {0, 0, 0, 0};
    #pragma unroll
    for (int ct = 0; ct < 8; ++ct)
        #pragma unroll
        for (int r = 0; r < 4; ++r) {
            nK[r] += accK[ct][r] * accK[ct][r];
            nQ[r] += accQ[ct][r] * accQ[ct][r];
        }
    #pragma unroll
    for (int r = 0; r < 4; ++r)
        #pragma unroll
        for (int o = 1; o < 16; o <<= 1) {
            nK[r] += __shfl_xor(nK[r], o, 64);
            nQ[r] += __shfl_xor(nQ[r], o, 64);
        }
    if (l15 == 0)
        #pragma unroll
        for (int r = 0; r < 4; ++r) {
            PK[ch][nw][quad * 4 + r] = nK[r];
            PQ[ch][nw][quad * 4 + r] = nQ[r];
        }
    if (lane < 16) vred[wave][l15] = vacc;
    __syncthreads();

    float ik[4], iq[4];
    #pragma unroll
    for (int r = 0; r < 4; ++r) {
        float sk = PK[0][nw][quad * 4 + r] + PK[1][nw][quad * 4 + r];
        float sq = PQ[0][nw][quad * 4 + r] + PQ[1][nw][quad * 4 + r];
        ik[r] = 1.f / fmaxf(sqrtf(sk), 1e-12f);
        iq[r] = 1.f / fmaxf(sqrtf(sq), 1e-12f);
    }
    #pragma unroll
    for (int ct = 0; ct < 8; ++ct)
        #pragma unroll
        for (int r = 0; r < 4; ++r) {
            size_t row = (size_t)(b * NHW + n0 + nw * 16 + quad * 4 + r) * NC
                       + ch * 128 + ct * 16 + l15;
            Kn[row] = f2bf(accK[ct][r] * ik[r]);
            Qn[row] = f2bf(accQ[ct][r] * iq[r]);
        }
    if (t < 16) {
        float4 s = {0.f, 0.f, 0.f, 0.f};
        #pragma unroll
        for (int w = 0; w < 8; ++w) {
            float4 p = vred[w][t];
            s.x += p.x; s.y += p.y; s.z += p.z; s.w += p.w;
        }
        float vb = value_b[0];
        s.x += vb; s.y += vb; s.z += vb; s.w += vb;
        *(float4*)(vout + b * NHW + n0 + t * 4) = s;
    }
}

// Per (b, 32 m-cols): 4 waves each own an n-quarter; 4 independent MFMA chains.
__global__ __launch_bounds__(256) void attn_kernel(
    const unsigned short* __restrict__ Kn,
    const unsigned short* __restrict__ Qn,
    const float* __restrict__ vbuf,
    float* __restrict__ R)
{
    const int b = blockIdx.y, m0 = blockIdx.x * 32;
    const int t = threadIdx.x, wave = t >> 6, lane = t & 63;
    const int l15 = lane & 15, quad = lane >> 4;

    short8 bf0[8], bf1[8];
    {
        const short* q0 = (const short*)Qn + (size_t)(b * NHW + m0 + l15) * NC + quad * 8;
        const short* q1 = q0 + 16 * NC;
        #pragma unroll
        for (int c = 0; c < 8; ++c) { bf0[c] = *(const short8*)(q0 + 32 * c);
                                      bf1[c] = *(const short8*)(q1 + 32 * c); }
    }
    const float* vb = vbuf + b * NHW;
    const int nstart = wave * 256;
    const short* ka = (const short*)Kn + (size_t)(b * NHW + nstart + l15) * NC + quad * 8;

    float z0 = 0.f, t0 = 0.f, z1 = 0.f, t1 = 0.f;
    for (int it = 0; it < 16; ++it, ka += 16 * NC) {
        short8 af[8];
        #pragma unroll
        for (int c = 0; c < 8; ++c) af[c] = *(const short8*)(ka + 32 * c);
        f32x4 a00 = {0,0,0,0}, a01 = {0,0,0,0}, a10 = {0,0,0,0}, a11 = {0,0,0,0};
        #pragma unroll
        for (int c = 0; c < 4; ++c) {
            a00 = __builtin_amdgcn_mfma_f32_16x16x32_bf16(af[c],     bf0[c],     a00, 0, 0, 0);
            a10 = __builtin_amdgcn_mfma_f32_16x16x32_bf16(af[c],     bf1[c],     a10, 0, 0, 0);
            a01 = __builtin_amdgcn_mfma_f32_16x16x32_bf16(af[c + 4], bf0[c + 4], a01, 0, 0, 0);
            a11 = __builtin_amdgcn_mfma_f32_16x16x32_bf16(af[c + 4], bf1[c + 4], a11, 0, 0, 0);
        }
        float4 vv = *(const float4*)(vb + nstart + it * 16 + quad * 4);
        #pragma unroll
        for (int r = 0; r < 4; ++r) {
            float e0 = __expf(a00[r] + a01[r]);
            float e1 = __expf(a10[r] + a11[r]);
            float vr = ((const float*)&vv)[r];
            z0 += e0; t0 += vr * e0;
            z1 += e1; t1 += vr * e1;
        }
    }
    z0 += __shfl_xor(z0, 16, 64); z0 += __shfl_xor(z0, 32, 64);
    t0 += __shfl_xor(t0, 16, 64); t0 += __shfl_xor(t0, 32, 64);
    z1 += __shfl_xor(z1, 16, 64); z1 += __shfl_xor(z1, 32, 64);
    t1 += __shfl_xor(t1, 16, 64); t1 += __shfl_xor(t1, 32, 64);

    __shared__ float zs[4][2][16], ts[4][2][16];
    if (lane < 16) {
        zs[wave][0][l15] = z0; ts[wave][0][l15] = t0;
        zs[wave][1][l15] = z1; ts[wave][1][l15] = t1;
    }
    __syncthreads();
    if (t < 32) {
        int ms = t >> 4, li = t & 15;
        float z = 0.f, tt = 0.f;
        #pragma unroll
        for (int w = 0; w < 4; ++w) { z += zs[w][ms][li]; tt += ts[w][ms][li]; }
        R[b * NHW + m0 + ms * 16 + li] = tt / z;
    }
}

// out[b,c,i,j] = 3x3 box sum over P[m] = R[b,m]*xc[b,c,m]  (xc bf16)
__global__ __launch_bounds__(256) void out_kernel(
    const unsigned short* __restrict__ xc,
    const float* __restrict__ R,
    float* __restrict__ out)
{
    const int bc = blockIdx.x;
    const int b  = bc >> 8;
    const int t  = threadIdx.x;
    __shared__ float P[NHW];

    const unsigned short* xp = xc + (size_t)bc * NHW;
    const float* rp = R + b * NHW;
    {
        ushort4 xv = *(const ushort4*)(xp + t * 4);
        float4  rv = *(const float4*)(rp + t * 4);
        P[t * 4 + 0] = rv.x * bf2f(xv.x);
        P[t * 4 + 1] = rv.y * bf2f(xv.y);
        P[t * 4 + 2] = rv.z * bf2f(xv.z);
        P[t * 4 + 3] = rv.w * bf2f(xv.w);
    }
    __syncthreads();
    for (int idx = t; idx < NCH * NCH; idx += 256) {
        int i = idx / NCH, j = idx - i * NCH;
        const float* pr = &P[i * 32 + j];
        float s = pr[0]  + pr[1]  + pr[2]
                + pr[32] + pr[33] + pr[34]
                + pr[64] + pr[65] + pr[66];
        out[(size_t)bc * (NCH * NCH) + idx] = s;
    }
}

extern "C" void kernel_launch(void* const* d_in, const int* in_sizes, int n_in,
                              void* d_out, int out_size, void* d_ws, size_t ws_size,
                              hipStream_t stream) {
    const float* batch   = (const float*)d_in[0];
    const float* key_w   = (const float*)d_in[1];
    const float* key_b   = (const float*)d_in[2];
    const float* query_w = (const float*)d_in[3];
    const float* query_b = (const float*)d_in[4];
    const float* value_w = (const float*)d_in[5];
    const float* value_b = (const float*)d_in[6];
    float* out = (float*)d_out;

    char* ws = (char*)d_ws;
    const size_t KQ = (size_t)NB * NHW * NC;            // 4,194,304 elems
    unsigned short* xc  = (unsigned short*)ws;                        // 8MB
    unsigned short* Kn  = xc + KQ;                                    // 8MB
    unsigned short* Qn  = Kn + KQ;                                    // 8MB
    unsigned short* kwb = Qn + KQ;                                    // 128KB
    unsigned short* qwb = kwb + NC * NC;                              // 128KB
    float* vbuf = (float*)(qwb + NC * NC);                            // 64KB
    float* Rbuf = vbuf + NB * NHW;                                    // 64KB

    wconv_kernel<<<32, 256, 0, stream>>>(key_w, query_w, kwb, qwb);
    fused_lin_kernel<<<dim3(16, NB), 512, 0, stream>>>(batch, value_w, value_b,
                                                       kwb, qwb, key_b, query_b,
                                                       xc, Kn, Qn, vbuf);
    attn_kernel<<<dim3(32, NB), 256, 0, stream>>>(Kn, Qn, vbuf, Rbuf);
    out_kernel<<<NB * NC, 256, 0, stream>>>(xc, Rbuf, out);
}